// Round 6
// baseline (99.777 us; speedup 1.0000x reference)
//
#include <hip/hip_runtime.h>

// NeuralCA: out = clip(x + sum_k sigmoid(10*(conv3x3_k(x) - r_k)) * (p_k - x), 0, 1)
// B=16, H=W=512, NK=16, fp32. VALU-issue-bound (8% HBM, MfmaUtil 0).
// R6 theory: R4->R5 marginal-cost fit gives c_trans ~= c_pk ~= 6 cyc, c_scalar ~= 3
// cyc effective -> v_pk_fma_f32 is HALF RATE (157.3TF spec = 2x 78.6 scalar, the 2x
// is the packing), so f2 packing bought nothing and its bc2() weight splats cost
// extra. This round: pure scalar minimal-op kernel, 15 instrs/px-k:
//   9 conv fma (weights as SGPR operands via addrspace(4) loads - no splats)
//   + 1 t-fma + v_exp_f32 + add + v_rcp_f32 + 2 accum.
// Saturation is self-correct: t>>0 -> e=inf -> rcp(inf)=0; t<<0 -> e=0 -> sig=1.

#define NK 16
#define BATCH 16
#define H 512
#define W 512
#define G2 14.4269504088896340f   // GAIN(=10) * log2(e)

#if __has_builtin(__builtin_amdgcn_exp2f)
#define EXP2F(x) __builtin_amdgcn_exp2f(x)
#else
#define EXP2F(x) exp2f(x)
#endif

// Constant address space -> guaranteed s_load (SGPR broadcast, free on SMEM pipe)
typedef const __attribute__((address_space(4))) float cfloat;

__global__ __launch_bounds__(256, 4) void nca_kernel(
    const float* __restrict__ x,
    const float* __restrict__ kernels,
    const float* __restrict__ reactants,
    const float* __restrict__ products,
    float* __restrict__ out)
{
    // One thread per 2x4 pixel tile. Tiles: 16 * 256 * 128 = 2^19 threads.
    const int idx = blockIdx.x * blockDim.x + threadIdx.x;
    const int w4 = (idx & 127) << 2;        // tile start col (128 tiles/row)
    const int h0 = ((idx >> 7) & 255) << 1; // tile start row
    const int b  = idx >> 15;

    const float* xb = x + (size_t)b * (H * W);

    // 4 rows x 6 cols scalar register window (rows h0-1 .. h0+2, halo 1 in w)
    float v[4][6];
#pragma unroll
    for (int r = 0; r < 4; ++r) {
        const int row = h0 + r - 1;
        if (row >= 0 && row < H) {
            const float* xr = xb + row * W;
            const float4 c = *(const float4*)(xr + w4);
            v[r][1] = c.x; v[r][2] = c.y; v[r][3] = c.z; v[r][4] = c.w;
            v[r][0] = (w4 > 0)     ? xr[w4 - 1] : 0.0f;   // zero pad left
            v[r][5] = (w4 + 4 < W) ? xr[w4 + 4] : 0.0f;   // zero pad right
        } else {
#pragma unroll
            for (int c = 0; c < 6; ++c) v[r][c] = 0.0f;   // zero pad top/bottom
        }
    }

    cfloat* kc = (cfloat*)kernels;
    cfloat* rc = (cfloat*)reactants;
    cfloat* pc = (cfloat*)products;

    // delta = (sum_k sig_k*p_k) - x*(sum_k sig_k)
    float s0[2][4] = {{0.f,0.f,0.f,0.f},{0.f,0.f,0.f,0.f}};  // sum sig
    float s1[2][4] = {{0.f,0.f,0.f,0.f},{0.f,0.f,0.f,0.f}};  // sum sig*p_k

#pragma unroll
    for (int k = 0; k < NK; ++k) {
        // All uniform scalars: s_load'ed, consumed directly as the 1-SGPR operand
        // of each v_fma_f32. No vector movs for weights.
        const float w0 = kc[k * 9 + 0], w1 = kc[k * 9 + 1], w2 = kc[k * 9 + 2];
        const float w3 = kc[k * 9 + 3], w4_ = kc[k * 9 + 4], w5 = kc[k * 9 + 5];
        const float w6 = kc[k * 9 + 6], w7 = kc[k * 9 + 7], w8 = kc[k * 9 + 8];
        const float c2 = G2 * rc[k];    // t = c2 - G2*N ; e = 2^t = exp(-10*(N-r_k))
        const float pk = pc[k];

#pragma unroll
        for (int py = 0; py < 2; ++py) {
#pragma unroll
            for (int p = 0; p < 4; ++p) {
                float n;
                n = v[py + 0][p + 0] * w0;
                n = fmaf(v[py + 0][p + 1], w1, n);
                n = fmaf(v[py + 0][p + 2], w2, n);
                n = fmaf(v[py + 1][p + 0], w3, n);
                n = fmaf(v[py + 1][p + 1], w4_, n);
                n = fmaf(v[py + 1][p + 2], w5, n);
                n = fmaf(v[py + 2][p + 0], w6, n);
                n = fmaf(v[py + 2][p + 1], w7, n);
                n = fmaf(v[py + 2][p + 2], w8, n);
                const float t = fmaf(-G2, n, c2);
                const float e = EXP2F(t);                      // v_exp_f32
                const float sig = __builtin_amdgcn_rcpf(1.0f + e);  // v_add + v_rcp
                s0[py][p] += sig;
                s1[py][p] = fmaf(sig, pk, s1[py][p]);
            }
        }
    }

#pragma unroll
    for (int py = 0; py < 2; ++py) {
        float4 o;
        float* op = &o.x;
#pragma unroll
        for (int p = 0; p < 4; ++p) {
            const float xv = v[py + 1][p + 1];
            float res = fmaf(-xv, s0[py][p], xv + s1[py][p]);
            op[p] = fminf(fmaxf(res, 0.0f), 1.0f);
        }
        *(float4*)(out + ((size_t)(b * H + h0 + py) * W + w4)) = o;
    }
}

extern "C" void kernel_launch(void* const* d_in, const int* in_sizes, int n_in,
                              void* d_out, int out_size, void* d_ws, size_t ws_size,
                              hipStream_t stream) {
    const float* x         = (const float*)d_in[0];
    const float* kernels   = (const float*)d_in[1];
    const float* reactants = (const float*)d_in[2];
    const float* products  = (const float*)d_in[3];
    float* out = (float*)d_out;

    const int total_tiles = BATCH * (H / 2) * (W / 4);  // 2^19
    nca_kernel<<<total_tiles / 256, 256, 0, stream>>>(x, kernels, reactants, products, out);
}

// Round 7
// 95.102 us; speedup vs baseline: 1.0492x; 1.0492x over previous
//
#include <hip/hip_runtime.h>

// NeuralCA: out = clip(x + sum_k sigmoid(10*(conv3x3_k(x) - r_k)) * (p_k - x), 0, 1)
// B=16, H=W=512, NK=16, fp32.
// R7 model (fits R1-R6): cost = sum instr*cyc with pk~4, scalar~2.5-3, trans~16 cyc
// (quarter rate) + ~35% stall tax. R4 (packed, 17 instr/pair-k) = 30us kernel; trans
// is 55% of its cycles. This round:
//  (a) batched reciprocal: 4 rcp per row-k -> 1 rcp + 9 muls (saves ~25 cyc/row-k);
//      requires clamping z<=28 so the 4-way product can't overflow (clamped sigma
//      = 3.7e-9 ~ 0, error < 4e-9).
//  (b) occupancy: 1x4 tile (3-row window, ~60-70 VGPR) + __launch_bounds__(256,6)
//      -> 6 waves/SIMD vs R4's 4, to cut the latency-stall tax.

#define NK 16
#define BATCH 16
#define H 512
#define W 512
#define G2 14.4269504088896340f   // GAIN(=10) * log2(e)

typedef float f2 __attribute__((ext_vector_type(2)));

#if __has_builtin(__builtin_amdgcn_exp2f)
#define EXP2F(x) __builtin_amdgcn_exp2f(x)
#else
#define EXP2F(x) exp2f(x)
#endif

#if __has_builtin(__builtin_elementwise_fma)
#define FMA2(a, b, c) __builtin_elementwise_fma((a), (b), (c))
#else
#define FMA2(a, b, c) ((a) * (b) + (c))   // fp-contract folds to fma.v2f32
#endif

#if __has_builtin(__builtin_elementwise_min)
#define MIN2(a, b) __builtin_elementwise_min((a), (b))
#else
static __device__ __forceinline__ f2 MIN2(f2 a, f2 b) {
    f2 r; r.x = fminf(a.x, b.x); r.y = fminf(a.y, b.y); return r;
}
#endif

static __device__ __forceinline__ f2 bc2(float s) { f2 r; r.x = s; r.y = s; return r; }

// Constant address space -> guaranteed s_load (SGPR broadcast)
typedef const __attribute__((address_space(4))) float cfloat;

__global__ __launch_bounds__(256, 6) void nca_kernel(
    const float* __restrict__ x,
    const float* __restrict__ kernels,
    const float* __restrict__ reactants,
    const float* __restrict__ products,
    float* __restrict__ out)
{
    // One thread per 1x4 pixel strip. 16*512*128 = 2^20 threads, 4096 blocks.
    const int idx = blockIdx.x * blockDim.x + threadIdx.x;
    const int w4 = (idx & 127) << 2;      // strip start col (128 strips/row)
    const int h  = (idx >> 7) & 511;
    const int b  = idx >> 16;

    const float* xb = x + (size_t)b * (H * W);

    // 3 rows x 6 cols window (halo 1 each side in w)
    float v[3][6];
#pragma unroll
    for (int r = 0; r < 3; ++r) {
        const int row = h + r - 1;
        if (row >= 0 && row < H) {
            const float* xr = xb + row * W;
            const float4 c = *(const float4*)(xr + w4);
            v[r][1] = c.x; v[r][2] = c.y; v[r][3] = c.z; v[r][4] = c.w;
            v[r][0] = (w4 > 0)     ? xr[w4 - 1] : 0.0f;   // zero pad left
            v[r][5] = (w4 + 4 < W) ? xr[w4 + 4] : 0.0f;   // zero pad right
        } else {
#pragma unroll
            for (int c = 0; c < 6; ++c) v[r][c] = 0.0f;   // zero pad top/bottom
        }
    }

    // Shifted float2 slices: sl[r][s] = {v[r][s], v[r][s+1]}, s = 0..4.
    // Output pair g (cols 2g,2g+1): tap c uses sl[r][2g+c]; center = sl[1][2g+1].
    f2 sl[3][5];
#pragma unroll
    for (int r = 0; r < 3; ++r)
#pragma unroll
        for (int s = 0; s < 5; ++s) { sl[r][s].x = v[r][s]; sl[r][s].y = v[r][s + 1]; }

    cfloat* kc = (cfloat*)kernels;
    cfloat* rc = (cfloat*)reactants;
    cfloat* pc = (cfloat*)products;

    f2 s0[2], s1[2];                       // sum sig, sum sig*p_k per pair
    s0[0] = bc2(0.0f); s0[1] = bc2(0.0f);
    s1[0] = bc2(0.0f); s1[1] = bc2(0.0f);

    const f2 mg2  = bc2(-G2);
    const f2 zcap = bc2(28.0f);            // e=2^z <= 2^28 so 4-way product < 2^120

#pragma unroll
    for (int k = 0; k < NK; ++k) {
        f2 wk[9];
#pragma unroll
        for (int i = 0; i < 9; ++i) wk[i] = bc2(kc[k * 9 + i]);
        const f2 c2 = bc2(G2 * rc[k]);     // z = c2 - G2*N ; e = 2^z = exp(-10*(N-r_k))
        const f2 pk = bc2(pc[k]);

        // conv + z for both pairs
        f2 d[2];                           // d = 1 + e
#pragma unroll
        for (int g = 0; g < 2; ++g) {
            f2 n = bc2(0.0f);
#pragma unroll
            for (int r = 0; r < 3; ++r)
#pragma unroll
                for (int c = 0; c < 3; ++c)
                    n = FMA2(sl[r][2 * g + c], wk[r * 3 + c], n);
            f2 z = FMA2(mg2, n, c2);
            z = MIN2(z, zcap);             // pk_min: overflow guard for 4-way rcp
            f2 e;
            e.x = EXP2F(z.x);              // v_exp_f32 (quarter-rate)
            e.y = EXP2F(z.y);
            d[g] = e + bc2(1.0f);          // pk add
        }

        // Batched reciprocal: 1 rcp + 9 muls replaces 4 rcps.
        const float t1 = d[0].x * d[0].y;
        const float t2 = d[1].x * d[1].y;
        const float r4 = __builtin_amdgcn_rcpf(t1 * t2);
        const float r01 = r4 * t2;         // 1/(d0x*d0y)
        const float r23 = r4 * t1;         // 1/(d1x*d1y)
        f2 sig0, sig1;
        sig0.x = r01 * d[0].y;             // 1/d0x
        sig0.y = r01 * d[0].x;             // 1/d0y
        sig1.x = r23 * d[1].y;
        sig1.y = r23 * d[1].x;

        s0[0] = s0[0] + sig0;              // pk add
        s0[1] = s0[1] + sig1;
        s1[0] = FMA2(sig0, pk, s1[0]);     // pk fma
        s1[1] = FMA2(sig1, pk, s1[1]);
    }

    float4 o;
#pragma unroll
    for (int g = 0; g < 2; ++g) {
        const f2 xv = sl[1][2 * g + 1];    // center pixels of pair
        f2 res = FMA2(-xv, s0[g], xv + s1[g]);
        res.x = fminf(fmaxf(res.x, 0.0f), 1.0f);
        res.y = fminf(fmaxf(res.y, 0.0f), 1.0f);
        if (g == 0) { o.x = res.x; o.y = res.y; }
        else        { o.z = res.x; o.w = res.y; }
    }
    *(float4*)(out + (size_t)idx * 4) = o;
}

extern "C" void kernel_launch(void* const* d_in, const int* in_sizes, int n_in,
                              void* d_out, int out_size, void* d_ws, size_t ws_size,
                              hipStream_t stream) {
    const float* x         = (const float*)d_in[0];
    const float* kernels   = (const float*)d_in[1];
    const float* reactants = (const float*)d_in[2];
    const float* products  = (const float*)d_in[3];
    float* out = (float*)d_out;

    const int total_strips = BATCH * H * (W / 4);  // 2^20
    nca_kernel<<<total_strips / 256, 256, 0, stream>>>(x, kernels, reactants, products, out);
}